// Round 1
// baseline (61.588 us; speedup 1.0000x reference)
//
#include <hip/hip_runtime.h>

#define N_NODES 207
#define N_EDGES 1722
#define N_SLOTS 288
#define L_DIM 24            // 2*12 feature channels
#define TOT_ENT (2 * N_EDGES)

// ---------------------------------------------------------------------------
// Kernel 1: build CSR incidence structure (node -> list of (neighbor, edge_id))
// Single block, 256 threads. Runs once per launch into d_ws.
// ---------------------------------------------------------------------------
__global__ __launch_bounds__(256) void build_csr_kernel(
    const int* __restrict__ edge_index,     // [2, N_EDGES]
    int* __restrict__ csr_off,              // [N_NODES + 1]
    unsigned int* __restrict__ entries)     // [TOT_ENT], packed nbr | (edge<<16)
{
    __shared__ int cnt[256];
    __shared__ int scan[256];
    __shared__ int cursor[N_NODES];
    const int tid = threadIdx.x;

    cnt[tid] = 0;
    __syncthreads();

    for (int e = tid; e < N_EDGES; e += 256) {
        int i = edge_index[e];
        int j = edge_index[N_EDGES + e];
        atomicAdd(&cnt[i], 1);
        atomicAdd(&cnt[j], 1);
    }
    __syncthreads();

    // Hillis-Steele inclusive scan over 256 slots (cnt[w]=0 for w>=N_NODES)
    int v = (tid < N_NODES) ? cnt[tid] : 0;
    scan[tid] = v;
    __syncthreads();
    for (int s = 1; s < 256; s <<= 1) {
        int t = (tid >= s) ? scan[tid - s] : 0;
        __syncthreads();
        scan[tid] += t;
        __syncthreads();
    }
    int excl = scan[tid] - v;   // exclusive prefix
    if (tid < N_NODES) { csr_off[tid] = excl; cursor[tid] = excl; }
    if (tid == 255)    { csr_off[N_NODES] = scan[255]; }
    __syncthreads();

    for (int e = tid; e < N_EDGES; e += 256) {
        int i = edge_index[e];
        int j = edge_index[N_EDGES + e];
        int pi = atomicAdd(&cursor[i], 1);
        entries[pi] = (unsigned int)j | ((unsigned int)e << 16);
        int pj = atomicAdd(&cursor[j], 1);
        entries[pj] = (unsigned int)i | ((unsigned int)e << 16);
    }
}

// ---------------------------------------------------------------------------
// Kernel 2: main fused reaction-diffusion kernel. One block per batch element.
// Each of 207 active threads owns one output node w and gathers over its
// incident edges, accumulating all 24 feature channels in registers.
// ---------------------------------------------------------------------------
__global__ __launch_bounds__(256) void rdgcn_main_kernel(
    const float* __restrict__ x_in,      // [B, 24, 207] (l-major)
    const float* __restrict__ w_react,   // [N_SLOTS, N_EDGES]
    const float* __restrict__ w_diff,    // [N_SLOTS, N_EDGES]
    const float* __restrict__ b_react,   // [N_SLOTS, N_NODES]
    const float* __restrict__ b_diff,    // [N_SLOTS, N_NODES]
    const float* __restrict__ w_self,    // [N_SLOTS, N_NODES]
    const int* __restrict__ ind,         // [B]
    const int* __restrict__ csr_off,     // [N_NODES + 1]
    const unsigned int* __restrict__ entries, // [TOT_ENT]
    float* __restrict__ out)             // [B, 207, 24]
{
    __shared__ float x_sh[N_NODES * L_DIM];   // [node][l], 96B rows, 16B aligned
    __shared__ float wr_sh[N_EDGES];
    __shared__ float wd_sh[N_EDGES];
    __shared__ unsigned int ent_sh[TOT_ENT];
    __shared__ int off_sh[N_NODES + 1];

    const int b   = blockIdx.x;
    const int tid = threadIdx.x;
    const int s   = ind[b];   // RESOLUTION == 1, so slot = ind directly

    // Stage x with transpose: global [l][v] -> LDS [v][l]
    const float* xg = x_in + (size_t)b * (N_NODES * L_DIM);
    for (int idx = tid; idx < N_NODES * L_DIM; idx += 256) {
        int l = idx / N_NODES;
        int vn = idx - l * N_NODES;
        x_sh[vn * L_DIM + l] = xg[idx];
    }
    // Stage this slot's edge-weight rows (coalesced, L2-shared across blocks)
    const float* wrg = w_react + (size_t)s * N_EDGES;
    const float* wdg = w_diff  + (size_t)s * N_EDGES;
    for (int e = tid; e < N_EDGES; e += 256) {
        wr_sh[e] = wrg[e];
        wd_sh[e] = wdg[e];
    }
    for (int k = tid; k < TOT_ENT; k += 256) ent_sh[k] = entries[k];
    for (int k = tid; k <= N_NODES; k += 256) off_sh[k] = csr_off[k];
    __syncthreads();

    const int w = tid;
    if (w < N_NODES) {
        float accr[L_DIM], accd[L_DIM];
        #pragma unroll
        for (int l = 0; l < L_DIM; ++l) { accr[l] = 0.f; accd[l] = 0.f; }
        float swr = 0.f, swd = 0.f;   // running degree sums d_r[w], d_d[w]

        const int beg = off_sh[w];
        const int end = off_sh[w + 1];
        for (int k = beg; k < end; ++k) {
            unsigned int en = ent_sh[k];
            int nbr = (int)(en & 0xffffu);
            int e   = (int)(en >> 16);
            float wr = wr_sh[e];
            float wd = wd_sh[e];
            swr += wr;
            swd += wd;
            const float* xr = &x_sh[nbr * L_DIM];
            #pragma unroll
            for (int l = 0; l < L_DIM; ++l) {
                float xv = xr[l];
                accr[l] = fmaf(wr, xv, accr[l]);
                accd[l] = fmaf(wd, xv, accd[l]);
            }
        }

        const float br  = b_react[s * N_NODES + w];
        const float bd  = b_diff [s * N_NODES + w];
        const float wsl = w_self [s * N_NODES + w];
        const float* xw = &x_sh[w * L_DIM];
        float* op = out + (size_t)b * (N_NODES * L_DIM) + (size_t)w * L_DIM;
        #pragma unroll
        for (int l = 0; l < L_DIM; ++l) {
            float xv = xw[l];
            // R = diag(d_r) + A_r  ->  (Rx)[w] = swr*xv + accr
            float reaction  = fmaf(swr, xv,  accr[l]) + br;
            // D = diag(d_d) - A_d  ->  (Dx)[w] = swd*xv - accd
            float diffusion = fmaf(swd, xv, -accd[l]) + bd;
            op[l] = tanhf(reaction) + diffusion + xv * (1.f + wsl);
        }
    }
}

extern "C" void kernel_launch(void* const* d_in, const int* in_sizes, int n_in,
                              void* d_out, int out_size, void* d_ws, size_t ws_size,
                              hipStream_t stream) {
    const float* x_in     = (const float*)d_in[0];
    const float* w_react  = (const float*)d_in[1];
    const float* w_diff   = (const float*)d_in[2];
    const float* b_react  = (const float*)d_in[3];
    const float* b_diff   = (const float*)d_in[4];
    const float* w_self   = (const float*)d_in[5];
    const int*   ind      = (const int*)d_in[6];
    const int*   edge_idx = (const int*)d_in[7];
    float* out = (float*)d_out;

    // Workspace layout: csr_off [208 ints] | entries [3444 u32]
    int* csr_off = (int*)d_ws;
    size_t off_bytes = ((size_t)(N_NODES + 1) * sizeof(int) + 255) & ~(size_t)255;
    unsigned int* entries = (unsigned int*)((char*)d_ws + off_bytes);

    build_csr_kernel<<<1, 256, 0, stream>>>(edge_idx, csr_off, entries);

    const int B = in_sizes[6];   // 1024 (size of ind)
    rdgcn_main_kernel<<<B, 256, 0, stream>>>(x_in, w_react, w_diff,
                                             b_react, b_diff, w_self,
                                             ind, csr_off, entries, out);
}

// Round 2
// 35.036 us; speedup vs baseline: 1.7578x; 1.7578x over previous
//
#include <hip/hip_runtime.h>

#define N_NODES 207
#define N_EDGES 1722
#define N_SLOTS 288
#define L_DIM 24            // 2*12 feature channels
#define XPAD 28             // padded x row stride (floats); 28 breaks the
                            // stride-24 bank pathology (8 quad positions vs 4)
#define TOT_ENT (2 * N_EDGES)

// ---------------------------------------------------------------------------
// Kernel 1: build CSR incidence structure (node -> list of (neighbor, edge_id))
// Single block, 256 threads. Runs once per launch into d_ws.
// ---------------------------------------------------------------------------
__global__ __launch_bounds__(256) void build_csr_kernel(
    const int* __restrict__ edge_index,     // [2, N_EDGES]
    int* __restrict__ csr_off,              // [N_NODES + 1]
    unsigned int* __restrict__ entries)     // [TOT_ENT], packed nbr | (edge<<16)
{
    __shared__ int cnt[256];
    __shared__ int scan[256];
    __shared__ int cursor[N_NODES];
    const int tid = threadIdx.x;

    cnt[tid] = 0;
    __syncthreads();

    for (int e = tid; e < N_EDGES; e += 256) {
        int i = edge_index[e];
        int j = edge_index[N_EDGES + e];
        atomicAdd(&cnt[i], 1);
        atomicAdd(&cnt[j], 1);
    }
    __syncthreads();

    int v = (tid < N_NODES) ? cnt[tid] : 0;
    scan[tid] = v;
    __syncthreads();
    for (int s = 1; s < 256; s <<= 1) {
        int t = (tid >= s) ? scan[tid - s] : 0;
        __syncthreads();
        scan[tid] += t;
        __syncthreads();
    }
    int excl = scan[tid] - v;   // exclusive prefix
    if (tid < N_NODES) { csr_off[tid] = excl; cursor[tid] = excl; }
    if (tid == 255)    { csr_off[N_NODES] = scan[255]; }
    __syncthreads();

    for (int e = tid; e < N_EDGES; e += 256) {
        int i = edge_index[e];
        int j = edge_index[N_EDGES + e];
        int pi = atomicAdd(&cursor[i], 1);
        entries[pi] = (unsigned int)j | ((unsigned int)e << 16);
        int pj = atomicAdd(&cursor[j], 1);
        entries[pj] = (unsigned int)i | ((unsigned int)e << 16);
    }
}

// fast tanh: 1 - 2/(e^{2x}+1). v_exp_f32 + v_rcp_f32, ~1e-6 abs error.
// e^{2x}=inf -> rcp(inf)=0 -> 1; e^{2x}->0 -> 1-2 = -1. Both limits correct.
__device__ __forceinline__ float fast_tanhf(float x) {
    float e2 = __expf(2.0f * x);
    return 1.0f - 2.0f * __builtin_amdgcn_rcpf(e2 + 1.0f);
}

// ---------------------------------------------------------------------------
// Kernel 2: main fused kernel. One block per batch element; thread w owns
// output node w, keeps all 24 channels x {reaction,diffusion} in registers.
// LDS: x (padded rows, float4-readable) + interleaved (wr,wd) per edge.
// entries/csr_off are single-use per thread -> read straight from global
// (13.8 KB total, L1-resident), keeping LDS at 37 KB -> 4 blocks/CU.
// ---------------------------------------------------------------------------
__global__ __launch_bounds__(256, 4) void rdgcn_main_kernel(
    const float* __restrict__ x_in,      // [B, 24, 207] (l-major)
    const float* __restrict__ w_react,   // [N_SLOTS, N_EDGES]
    const float* __restrict__ w_diff,    // [N_SLOTS, N_EDGES]
    const float* __restrict__ b_react,   // [N_SLOTS, N_NODES]
    const float* __restrict__ b_diff,    // [N_SLOTS, N_NODES]
    const float* __restrict__ w_self,    // [N_SLOTS, N_NODES]
    const int* __restrict__ ind,         // [B]
    const int* __restrict__ csr_off,     // [N_NODES + 1]
    const unsigned int* __restrict__ entries, // [TOT_ENT]
    float* __restrict__ out)             // [B, 207, 24]
{
    __shared__ float  x_sh[N_NODES * XPAD];   // 23184 B, rows 112B (16B aligned)
    __shared__ float2 wrd_sh[N_EDGES];        // 13776 B, (wr, wd) interleaved

    const int b   = blockIdx.x;
    const int tid = threadIdx.x;
    const int s   = ind[b];   // RESOLUTION == 1

    // Stage x: thread v gathers its node row (coalesced global reads per l),
    // writes 6 x float4 (uniform 8 touches/bank = LDS minimum).
    const float* xg = x_in + (size_t)b * (N_NODES * L_DIM);
    if (tid < N_NODES) {
        float row[L_DIM];
        #pragma unroll
        for (int l = 0; l < L_DIM; ++l) row[l] = xg[l * N_NODES + tid];
        float4* dst = reinterpret_cast<float4*>(&x_sh[tid * XPAD]);
        #pragma unroll
        for (int c = 0; c < 6; ++c)
            dst[c] = make_float4(row[4*c], row[4*c+1], row[4*c+2], row[4*c+3]);
    }
    // Stage this slot's edge weights, interleaved for one b64 read per entry.
    {
        const float* wrg = w_react + (size_t)s * N_EDGES;
        const float* wdg = w_diff  + (size_t)s * N_EDGES;
        for (int e = tid; e < N_EDGES; e += 256)
            wrd_sh[e] = make_float2(wrg[e], wdg[e]);
    }
    __syncthreads();

    const int w = tid;
    if (w < N_NODES) {
        float accr[L_DIM], accd[L_DIM];
        #pragma unroll
        for (int l = 0; l < L_DIM; ++l) { accr[l] = 0.f; accd[l] = 0.f; }
        float swr = 0.f, swd = 0.f;   // running degrees d_r[w], d_d[w]

        const int beg = csr_off[w];
        const int end = csr_off[w + 1];
        // software-pipeline the (L1-resident) entry fetch over the FMA body
        unsigned int en_next = (beg < end) ? entries[beg] : 0u;
        for (int k = beg; k < end; ++k) {
            const unsigned int en = en_next;
            if (k + 1 < end) en_next = entries[k + 1];
            const int nbr = (int)(en & 0xffffu);
            const int e   = (int)(en >> 16);
            const float2 wv = wrd_sh[e];
            swr += wv.x;
            swd += wv.y;
            const float4* xr = reinterpret_cast<const float4*>(&x_sh[nbr * XPAD]);
            #pragma unroll
            for (int c = 0; c < 6; ++c) {
                const float4 xc = xr[c];
                accr[4*c+0] = fmaf(wv.x, xc.x, accr[4*c+0]);
                accd[4*c+0] = fmaf(wv.y, xc.x, accd[4*c+0]);
                accr[4*c+1] = fmaf(wv.x, xc.y, accr[4*c+1]);
                accd[4*c+1] = fmaf(wv.y, xc.y, accd[4*c+1]);
                accr[4*c+2] = fmaf(wv.x, xc.z, accr[4*c+2]);
                accd[4*c+2] = fmaf(wv.y, xc.z, accd[4*c+2]);
                accr[4*c+3] = fmaf(wv.x, xc.w, accr[4*c+3]);
                accd[4*c+3] = fmaf(wv.y, xc.w, accd[4*c+3]);
            }
        }

        const float br  = b_react[s * N_NODES + w];
        const float bd  = b_diff [s * N_NODES + w];
        const float wsl = w_self [s * N_NODES + w];
        const float4* xw4 = reinterpret_cast<const float4*>(&x_sh[w * XPAD]);
        float4* op4 = reinterpret_cast<float4*>(out + (size_t)b * (N_NODES * L_DIM)
                                                    + (size_t)w * L_DIM);
        #pragma unroll
        for (int c = 0; c < 6; ++c) {
            const float4 xc = xw4[c];
            float4 o;
            {
                float re = fmaf(swr, xc.x,  accr[4*c+0]) + br;
                float di = fmaf(swd, xc.x, -accd[4*c+0]) + bd;
                o.x = fast_tanhf(re) + di + fmaf(xc.x, wsl, xc.x);
            }
            {
                float re = fmaf(swr, xc.y,  accr[4*c+1]) + br;
                float di = fmaf(swd, xc.y, -accd[4*c+1]) + bd;
                o.y = fast_tanhf(re) + di + fmaf(xc.y, wsl, xc.y);
            }
            {
                float re = fmaf(swr, xc.z,  accr[4*c+2]) + br;
                float di = fmaf(swd, xc.z, -accd[4*c+2]) + bd;
                o.z = fast_tanhf(re) + di + fmaf(xc.z, wsl, xc.z);
            }
            {
                float re = fmaf(swr, xc.w,  accr[4*c+3]) + br;
                float di = fmaf(swd, xc.w, -accd[4*c+3]) + bd;
                o.w = fast_tanhf(re) + di + fmaf(xc.w, wsl, xc.w);
            }
            op4[c] = o;
        }
    }
}

extern "C" void kernel_launch(void* const* d_in, const int* in_sizes, int n_in,
                              void* d_out, int out_size, void* d_ws, size_t ws_size,
                              hipStream_t stream) {
    const float* x_in     = (const float*)d_in[0];
    const float* w_react  = (const float*)d_in[1];
    const float* w_diff   = (const float*)d_in[2];
    const float* b_react  = (const float*)d_in[3];
    const float* b_diff   = (const float*)d_in[4];
    const float* w_self   = (const float*)d_in[5];
    const int*   ind      = (const int*)d_in[6];
    const int*   edge_idx = (const int*)d_in[7];
    float* out = (float*)d_out;

    // Workspace layout: csr_off [208 ints] | entries [3444 u32]
    int* csr_off = (int*)d_ws;
    size_t off_bytes = ((size_t)(N_NODES + 1) * sizeof(int) + 255) & ~(size_t)255;
    unsigned int* entries = (unsigned int*)((char*)d_ws + off_bytes);

    build_csr_kernel<<<1, 256, 0, stream>>>(edge_idx, csr_off, entries);

    const int B = in_sizes[6];   // 1024 (size of ind)
    rdgcn_main_kernel<<<B, 256, 0, stream>>>(x_in, w_react, w_diff,
                                             b_react, b_diff, w_self,
                                             ind, csr_off, entries, out);
}